// Round 11
// baseline (85.036 us; speedup 1.0000x reference)
//
#include <hip/hip_runtime.h>

typedef __attribute__((ext_vector_type(8))) short bf16x8;
typedef __attribute__((ext_vector_type(4))) float f32x4;
typedef __attribute__((ext_vector_type(4))) short s16x4;

__device__ __forceinline__ unsigned short f2bf(float f) {
    unsigned int u = __builtin_bit_cast(unsigned int, f);
    u += 0x7fffu + ((u >> 16) & 1u);   // round-to-nearest-even
    return (unsigned short)(u >> 16);
}
__device__ __forceinline__ float bf2f(unsigned short h) {
    return __builtin_bit_cast(float, ((unsigned int)h) << 16);
}

// Kernel 1: A[i][j] = (i==j) ? 0 : sum_d w[i,field[j],d] * w[j,field[i],d]
// Symmetric, bit-identical across the diagonal. Packed bf16 in MFMA fragment
// order: apk[((kt*8+nt)*64+lane)*8+r] <-> A[kt*32+(lane>>4)*8+r][nt*16+(lane&15)].
__global__ void build_A_kernel(const float* __restrict__ w, const int* __restrict__ field,
                               unsigned short* __restrict__ apk) {
    int idx = blockIdx.x * 128 + threadIdx.x;   // 0..16383
    int i = idx >> 7, j = idx & 127;
    const float* wi = w + (i * 16 + field[j]) * 16;
    const float* wj = w + (j * 16 + field[i]) * 16;
    float s = 0.f;
#pragma unroll
    for (int d = 0; d < 16; ++d) s += wi[d] * wj[d];
    if (i == j) s = 0.f;
    int kt = i >> 5, g = (i >> 3) & 3, r = i & 7;
    int nt = j >> 4, c = j & 15;
    apk[((kt * 8 + nt) * 64 + (g * 16 + c)) * 8 + r] = f2bf(s);
}

// Kernel 2: EXACT R3 structure (21.3us champion), wrapped in a runtime
// `repeat` pass loop for PROFILING VISIBILITY: each pass recomputes and
// rewrites identical outputs (idempotent, deterministic). repeat=8 stretches
// the kernel past the harness' 40us fill dispatches so its counters appear
// in the rocprof top-5. Diagnostic round — revert repeat next round.
__global__ __launch_bounds__(256, 2)
void ffm_kernel(const float* __restrict__ x, const unsigned short* __restrict__ apk,
                float* __restrict__ out, int nTiles, int tilesPerWG, int repeat) {
    __shared__ __align__(16) unsigned short Xl[2][64 * 128];  // 2 x 16 KiB bf16, swizzled
    const int tid  = threadIdx.x;
    const int lane = tid & 63;
    const int wv   = tid >> 6;     // wave 0..3 owns rows [wv*16, wv*16+16)
    const int g    = lane >> 4;
    const int c    = lane & 15;

    const int tile0 = blockIdx.x * tilesPerWG;
    if (tile0 >= nTiles) return;

    // Cache the whole interaction matrix as MFMA fragments in registers (128 VGPR).
    bf16x8 bfrag[4][8];
#pragma unroll
    for (int kt = 0; kt < 4; ++kt)
#pragma unroll
        for (int nt = 0; nt < 8; ++nt)
            bfrag[kt][nt] = *reinterpret_cast<const bf16x8*>(apk + ((kt * 8 + nt) * 64 + lane) * 8);

    const int myrow = wv * 16 + c;
    const int rowbase = myrow * 128;
    const int xv = (myrow & 7) << 3;

    int buf = 0;
    for (int p = 0; p < repeat; ++p) {
        // First-tile prefetch (per pass, as in R3's prologue).
        f32x4 xr[8];
        {
            const f32x4* src = reinterpret_cast<const f32x4*>(x) + (size_t)tile0 * 2048;
#pragma unroll
            for (int i = 0; i < 8; ++i) xr[i] = src[i * 256 + tid];
        }

        for (int t = 0; t < tilesPerWG; ++t) {
            int tile = tile0 + t;
            if (tile >= nTiles) break;

            // Stage regs -> LDS bf16, XOR swizzle (short idx ^= (row&7)<<3).
#pragma unroll
            for (int i = 0; i < 8; ++i) {
                int row = i * 8 + (tid >> 5);
                int k   = (tid & 31) * 4;
                int sw  = row * 128 + (k ^ ((row & 7) << 3));
                s16x4 s4;
                s4.x = (short)f2bf(xr[i][0]);
                s4.y = (short)f2bf(xr[i][1]);
                s4.z = (short)f2bf(xr[i][2]);
                s4.w = (short)f2bf(xr[i][3]);
                *reinterpret_cast<s16x4*>(&Xl[buf][sw]) = s4;
            }
            // Prefetch next tile before the barrier (R3 schedule).
            if (t + 1 < tilesPerWG && tile + 1 < nTiles) {
                const f32x4* src = reinterpret_cast<const f32x4*>(x) + (size_t)(tile + 1) * 2048;
#pragma unroll
                for (int i = 0; i < 8; ++i) xr[i] = src[i * 256 + tid];
            }
            __syncthreads();

            // Yt = A(128x128) * X^T(128x16): acc[q] = Y[myrow][q*16 + g*4 + r].
            f32x4 acc[8];
#pragma unroll
            for (int q = 0; q < 8; ++q) acc[q] = (f32x4){0.f, 0.f, 0.f, 0.f};
#pragma unroll
            for (int kt = 0; kt < 4; ++kt) {
                int k0 = kt * 32 + g * 8;
                bf16x8 xa = *reinterpret_cast<const bf16x8*>(
                    &Xl[buf][rowbase + (k0 ^ xv)]);
#pragma unroll
                for (int q = 0; q < 8; ++q)
                    acc[q] = __builtin_amdgcn_mfma_f32_16x16x32_bf16(bfrag[kt][q], xa, acc[q], 0, 0, 0);
            }

            // Epilogue: sacc = sum over this lane's 32 i's of X[m][i]*Y[m][i].
            float sacc = 0.f;
#pragma unroll
            for (int q = 0; q < 8; ++q) {
                int ix = q * 16 + g * 4;
                s16x4 xs = *reinterpret_cast<const s16x4*>(&Xl[buf][rowbase + (ix ^ xv)]);
                sacc += bf2f((unsigned short)xs.x) * acc[q][0];
                sacc += bf2f((unsigned short)xs.y) * acc[q][1];
                sacc += bf2f((unsigned short)xs.z) * acc[q][2];
                sacc += bf2f((unsigned short)xs.w) * acc[q][3];
            }
            sacc += __shfl_xor(sacc, 16, 64);
            sacc += __shfl_xor(sacc, 32, 64);
            if (g == 0) out[(size_t)tile * 64 + myrow] = 0.5f * sacc;

            buf ^= 1;
        }
    }
}

extern "C" void kernel_launch(void* const* d_in, const int* in_sizes, int n_in,
                              void* d_out, int out_size, void* d_ws, size_t ws_size,
                              hipStream_t stream) {
    const float* x     = (const float*)d_in[0];
    const float* w     = (const float*)d_in[1];
    const int*   field = (const int*)d_in[2];
    float* outp        = (float*)d_out;
    unsigned short* apk = (unsigned short*)d_ws;   // 32 KiB packed A

    int B = in_sizes[0] / 128;
    build_A_kernel<<<128, 128, 0, stream>>>(w, field, apk);

    int nTiles = B / 64;                   // 2048 for B=131072
    const int TPW = 4;
    int grid = (nTiles + TPW - 1) / TPW;   // 512 = exactly 2 blocks/CU
    const int REPEAT = 8;                  // diagnostic: expose counters past the 40us fills
    ffm_kernel<<<grid, 256, 0, stream>>>(x, apk, outp, nTiles, TPW, REPEAT);
}